// Round 4
// baseline (405.430 us; speedup 1.0000x reference)
//
#include <hip/hip_runtime.h>
#include <hip/hip_bf16.h>

// Problem constants
constexpr int B_ = 512;
constexpr int T_ = 128;
constexpr int D_ = 768;
constexpr int CD_ = 192;
constexpr int SD_ = 128;
constexpr int P_ = 128;
constexpr int FEAT_ = 321;   // CD + SD + 1
constexpr float LN_EPS_ = 1e-5f;

constexpr size_t REP_SZ   = (size_t)B_ * 2 * D_;     // 786432 floats
constexpr size_t DN16_FLT = (size_t)P_ * D_ / 2;     // 98304 u16 = 49152 floats

typedef __attribute__((ext_vector_type(8))) short short8;   // 8 bf16 (4 VGPRs)
typedef __attribute__((ext_vector_type(4))) float f32x4;

// float -> bf16 RNE
__device__ __forceinline__ unsigned short f2bf(float x) {
    unsigned u = __float_as_uint(x);
    return (unsigned short)((u + 0x7FFFu + ((u >> 16) & 1u)) >> 16);
}
__device__ __forceinline__ float bf2f(unsigned short h) {
    return __uint_as_float((unsigned)h << 16);
}

// ---------------------------------------------------------------------------
// Kernel 1: dirs_n = dirs / ||dirs||, emitted as bf16  (one block per dir)
// ---------------------------------------------------------------------------
__global__ __launch_bounds__(256) void k_dirs(const float* __restrict__ dirs,
                                              unsigned short* __restrict__ dn16) {
    int p = blockIdx.x;
    int tid = threadIdx.x;
    float s = 0.f;
    for (int d = tid; d < D_; d += 256) {
        float v = dirs[(size_t)p * D_ + d];
        s = fmaf(v, v, s);
    }
    __shared__ float red[256];
    red[tid] = s;
    __syncthreads();
    for (int off = 128; off > 0; off >>= 1) {
        if (tid < off) red[tid] += red[tid + off];
        __syncthreads();
    }
    float inv = 1.0f / sqrtf(red[0]);
    for (int d = tid; d < D_; d += 256) {
        dn16[(size_t)p * D_ + d] = f2bf(dirs[(size_t)p * D_ + d] * inv);
    }
}

// ---------------------------------------------------------------------------
// Kernel 2: rep = [cls | mmean0 - mmean1]  (one block per batch, streaming)
// ---------------------------------------------------------------------------
__global__ __launch_bounds__(256) void k_rep(const float* __restrict__ H,
                                             const int* __restrict__ tt,
                                             const int* __restrict__ attn,
                                             float* __restrict__ rep) {
    int b = blockIdx.x;
    int tid = threadIdx.x;
    __shared__ float m0s[T_], m1s[T_];
    __shared__ int ncnt[2];
    if (tid < 2) ncnt[tid] = 0;
    __syncthreads();
    if (tid < T_) {
        int t = tt[b * T_ + tid];
        int a = attn[b * T_ + tid];
        float m0 = (t == 0 && a == 1) ? 1.f : 0.f;
        float m1 = (t == 1 && a == 1) ? 1.f : 0.f;
        m0s[tid] = m0;
        m1s[tid] = m1;
        if (m0 > 0.f) atomicAdd(&ncnt[0], 1);
        if (m1 > 0.f) atomicAdd(&ncnt[1], 1);
    }
    __syncthreads();
    float inv0 = 1.f / (float)max(ncnt[0], 1);
    float inv1 = 1.f / (float)max(ncnt[1], 1);
    const float* Hb = H + (size_t)b * T_ * D_;
    float* repb = rep + (size_t)b * 2 * D_;
#pragma unroll
    for (int pass = 0; pass < 3; ++pass) {
        int d = pass * 256 + tid;
        float s0 = 0.f, s1 = 0.f;
#pragma unroll 8
        for (int t = 0; t < T_; ++t) {
            float h = Hb[(size_t)t * D_ + d];
            s0 = fmaf(h, m0s[t], s0);
            s1 = fmaf(h, m1s[t], s1);
        }
        repb[d] = Hb[d];
        repb[D_ + d] = s0 * inv0 - s1 * inv1;
    }
}

// ---------------------------------------------------------------------------
// Kernel 3: MFMA proj GEMM (full 128x128 tile, bf16, reg-prefetch dbuf LDS,
//           raw barriers, XOR-swizzled stage) + key-rank + paired diff.
// One 512-thread block per batch.
// ---------------------------------------------------------------------------
constexpr int NIT_ = 24;            // 768 / 32
constexpr int BUF_U16_ = 8192;      // A 4096 + B 4096 u16 per buffer (16 KB)

__global__ __launch_bounds__(512, 4) void k_projsort(const float* __restrict__ H,
                                                     const int* __restrict__ tt,
                                                     const int* __restrict__ attn,
                                                     const unsigned short* __restrict__ dn16,
                                                     float* __restrict__ d_ot) {
    const int b = blockIdx.x;
    const int tid = threadIdx.x;

    __shared__ __align__(16) unsigned short stage[2 * BUF_U16_];  // 32 KB
    __shared__ __align__(16) unsigned short proj16[T_ * 128];     // 32 KB
    __shared__ float m0s[T_], m1s[T_];
    __shared__ unsigned char rlist[T_];
    __shared__ int ncnt[2];
    __shared__ float dred[512];

    // rank->t index tables overlay the (dead after GEMM) stage buffer
    unsigned char* xb = (unsigned char*)stage;           // [64][128]
    unsigned char* yb = xb + 64 * 128;                   // [64][128]

    // --- phase 0: masks, counts, group-compacted row list ---
    if (tid < 2) ncnt[tid] = 0;
    __syncthreads();
    if (tid < T_) {
        int t = tt[b * T_ + tid];
        int a = attn[b * T_ + tid];
        float m0 = (t == 0 && a == 1) ? 1.f : 0.f;
        float m1 = (t == 1 && a == 1) ? 1.f : 0.f;
        m0s[tid] = m0;
        m1s[tid] = m1;
        if (m0 > 0.f) atomicAdd(&ncnt[0], 1);
        if (m1 > 0.f) atomicAdd(&ncnt[1], 1);
    }
    __syncthreads();
    const int n0 = ncnt[0], n1 = ncnt[1];
    const int ntot = n0 + n1;
    if (tid < T_) {
        float me0 = m0s[tid], me1 = m1s[tid];
        if (me0 > 0.f || me1 > 0.f) {
            bool g1 = (me1 > 0.f);
            const float* ms = g1 ? m1s : m0s;
            int pos = g1 ? n0 : 0;
            for (int j = 0; j < tid; ++j) pos += (ms[j] > 0.f) ? 1 : 0;
            rlist[pos] = (unsigned char)tid;
        }
    }
    __syncthreads();

    // --- phase 1: GEMM proj[t][p] = sum_k H[b,t,k] * dn[p,k] via bf16 MFMA ---
    // Staging map: thread -> (row srow, phys 16B chunk scp); logical chunk
    // XOR-swizzled so ds_read_b128 fragment reads are bank-conflict-free.
    const float* Hb = H + (size_t)b * T_ * D_;
    const int srow = tid >> 2;                 // 0..127
    const int scp  = tid & 3;                  // phys chunk (16 B)
    const int sclog = scp ^ ((srow >> 1) & 3); // logical chunk (swizzle, involution)
    const float* gA = Hb + (size_t)srow * D_ + sclog * 8;
    const unsigned short* gB = dn16 + (size_t)srow * D_ + sclog * 8;
    const int dOff = srow * 32 + scp * 8;      // u16 offset within A region

    // MFMA fragment geometry: 8 waves = 2 (row) x 4 (col)
    const int wv = tid >> 6;
    const int wr = wv >> 2;           // 0..1 : rows 64*wr..
    const int wc = wv & 3;            // 0..3 : cols 32*wc..
    const int lane = tid & 63;
    const int fr = lane & 15;
    const int kg = lane >> 4;
    const int ck = (kg ^ ((fr >> 1) & 3)) * 8;           // swizzled k-chunk
    const int baseA = (64 * wr + fr) * 32 + ck;          // + 512*m
    const int baseB = 4096 + (32 * wc + fr) * 32 + ck;   // + 512*n

    f32x4 acc[4][2];
#pragma unroll
    for (int m = 0; m < 4; ++m)
#pragma unroll
        for (int n = 0; n < 2; ++n) acc[m][n] = (f32x4){0.f, 0.f, 0.f, 0.f};

    // prologue: prefetch k0 = 0
    float4 a0 = *reinterpret_cast<const float4*>(gA);
    float4 a1 = *reinterpret_cast<const float4*>(gA + 4);
    short8 bv = *reinterpret_cast<const short8*>(gB);

    for (int it = 0; it < NIT_; ++it) {
        const int cur = it & 1;
        unsigned short* sb = stage + cur * BUF_U16_;
        // convert + stage current tile
        short8 w;
        w[0] = (short)f2bf(a0.x); w[1] = (short)f2bf(a0.y);
        w[2] = (short)f2bf(a0.z); w[3] = (short)f2bf(a0.w);
        w[4] = (short)f2bf(a1.x); w[5] = (short)f2bf(a1.y);
        w[6] = (short)f2bf(a1.z); w[7] = (short)f2bf(a1.w);
        *reinterpret_cast<short8*>(sb + dOff) = w;
        *reinterpret_cast<short8*>(sb + 4096 + dOff) = bv;
        // prefetch next tile (stays in flight across both barriers + MFMA)
        if (it < NIT_ - 1) {
            int k = (it + 1) * 32;
            a0 = *reinterpret_cast<const float4*>(gA + k);
            a1 = *reinterpret_cast<const float4*>(gA + k + 4);
            bv = *reinterpret_cast<const short8*>(gB + k);
        }
        asm volatile("s_waitcnt lgkmcnt(0)" ::: "memory");
        __builtin_amdgcn_s_barrier();
        asm volatile("" ::: "memory");

        const unsigned short* sr = stage + cur * BUF_U16_;
        short8 af[4], bf_[2];
#pragma unroll
        for (int m = 0; m < 4; ++m)
            af[m] = *reinterpret_cast<const short8*>(sr + baseA + 512 * m);
#pragma unroll
        for (int n = 0; n < 2; ++n)
            bf_[n] = *reinterpret_cast<const short8*>(sr + baseB + 512 * n);
#pragma unroll
        for (int m = 0; m < 4; ++m)
#pragma unroll
            for (int n = 0; n < 2; ++n)
                acc[m][n] = __builtin_amdgcn_mfma_f32_16x16x32_bf16(af[m], bf_[n], acc[m][n], 0, 0, 0);

        asm volatile("" ::: "memory");
        __builtin_amdgcn_s_barrier();
        asm volatile("" ::: "memory");
    }

    // epilogue: write proj16 (C/D layout: col=lane&15, row=(lane>>4)*4+reg)
#pragma unroll
    for (int m = 0; m < 4; ++m)
#pragma unroll
        for (int n = 0; n < 2; ++n) {
            int row0 = 64 * wr + 16 * m + kg * 4;
            int col = 32 * wc + 16 * n + fr;
#pragma unroll
            for (int r = 0; r < 4; ++r)
                proj16[(row0 + r) * 128 + col] = f2bf(acc[m][n][r]);
        }
    __syncthreads();

    // --- phase 2: ranking via sortable-u32 keys (bf16 values) ---
    const int mmv = min(n0, n1);      // <= 64 since n0+n1 <= 128
    const int c = tid & 127;
    const int q = tid >> 7;           // 0..3
    unsigned kv[32];
    int cnt[32];
#pragma unroll
    for (int ii = 0; ii < 32; ++ii) {
        int p = q * 32 + ii;
        unsigned key = 0xFFFFFFFFu;
        if (p < ntot) {
            int t = rlist[p];
            unsigned u = ((unsigned)proj16[t * 128 + c]) << 16;
            unsigned su = u ^ (unsigned)(((int)u >> 31) | 0x80000000);
            key = ((unsigned)(p >= n0) << 31) | ((su >> 8) << 7) | (unsigned)p;
        }
        kv[ii] = key;
        cnt[ii] = 0;
    }
    int lo, hi;
    {
        int plo = q * 32, phi = q * 32 + 32;
        if (phi <= n0)      { lo = 0;  hi = n0;   }   // pure group-0 chunk
        else if (plo >= n0) { lo = n0; hi = ntot; }   // pure group-1 chunk
        else                { lo = 0;  hi = ntot; }   // straddler
    }
    for (int j = lo; j < hi; ++j) {
        int tj = rlist[j];
        unsigned u = ((unsigned)proj16[tj * 128 + c]) << 16;
        unsigned su = u ^ (unsigned)(((int)u >> 31) | 0x80000000);
        unsigned kw = ((unsigned)(j >= n0) << 31) | ((su >> 8) << 7) | (unsigned)j;
#pragma unroll
        for (int ii = 0; ii < 32; ++ii) cnt[ii] += (kw < kv[ii]) ? 1 : 0;
    }
#pragma unroll
    for (int ii = 0; ii < 32; ++ii) {
        int p = q * 32 + ii;
        if (p < ntot) {
            int rank = cnt[ii] - ((p >= n0 && lo == 0) ? n0 : 0);
            if (rank < mmv) {
                unsigned char* buf = (p >= n0) ? yb : xb;
                buf[rank * 128 + c] = rlist[p];
            }
        }
    }
    __syncthreads();

    // --- phase 3: paired diff per column, max over columns ---
    float part = 0.f;
    for (int r = q; r < mmv; r += 4) {
        int xt = xb[r * 128 + c], yt = yb[r * 128 + c];
        part += fabsf(bf2f(proj16[xt * 128 + c]) - bf2f(proj16[yt * 128 + c]));
    }
    dred[tid] = part;
    __syncthreads();
    if (tid < 128) {
        float invm = 1.f / (float)max(mmv, 1);
        dred[tid] = (dred[tid] + dred[tid + 128] + dred[tid + 256] + dred[tid + 384]) * invm;
    }
    __syncthreads();
    if (tid < 64) {
        float m = fmaxf(dred[tid], dred[tid + 64]);
#pragma unroll
        for (int off = 32; off > 0; off >>= 1) m = fmaxf(m, __shfl_xor(m, off));
        if (tid == 0) d_ot[b] = m;    // one block per batch: direct store
    }
}

// ---------------------------------------------------------------------------
// Kernel 4: head — C/S GEMV + gate + LayerNorm + logits.
// 320 threads (1 output each), 4 batches per block, wave-parallel LN.
// ---------------------------------------------------------------------------
__global__ __launch_bounds__(320) void k_head(const float* __restrict__ rep,
                                              const float* __restrict__ Wc,
                                              const float* __restrict__ bc,
                                              const float* __restrict__ Ws,
                                              const float* __restrict__ bs,
                                              const float* __restrict__ gate,
                                              const float* __restrict__ lng,
                                              const float* __restrict__ lnb,
                                              const float* __restrict__ Wcls,
                                              const float* __restrict__ bcls,
                                              const float* __restrict__ d_ot,
                                              float* __restrict__ out) {
    int b0 = blockIdx.x * 4;
    int tid = threadIdx.x;
    __shared__ __align__(16) float repS[4 * 1536];   // 24 KB
    __shared__ float featS[4 * FEAT_];

    const float4* repg = reinterpret_cast<const float4*>(rep + (size_t)b0 * 1536);
    float4* repl = reinterpret_cast<float4*>(repS);
    for (int i = tid; i < 1536; i += 320) repl[i] = repg[i];
    __syncthreads();

    float g = 1.f / (1.f + expf(-gate[0]));

    {   // each thread: one output o over 4 batches
        int o = tid;  // 0..319
        bool isC = o < CD_;
        const float* w = isC ? (Wc + (size_t)o * 1536) : (Ws + (size_t)(o - CD_) * 1536);
        float bias = isC ? bc[o] : bs[o - CD_];
        float scale = isC ? (1.f - g) : g;
        const float4* w4 = reinterpret_cast<const float4*>(w);
        float a0 = 0.f, a1 = 0.f, a2 = 0.f, a3 = 0.f;
        for (int k4 = 0; k4 < 384; ++k4) {
            float4 wv = w4[k4];
            float4 r0 = repl[k4];
            float4 r1 = repl[384 + k4];
            float4 r2 = repl[768 + k4];
            float4 r3 = repl[1152 + k4];
            a0 += fmaf(wv.x, r0.x, fmaf(wv.y, r0.y, fmaf(wv.z, r0.z, wv.w * r0.w)));
            a1 += fmaf(wv.x, r1.x, fmaf(wv.y, r1.y, fmaf(wv.z, r1.z, wv.w * r1.w)));
            a2 += fmaf(wv.x, r2.x, fmaf(wv.y, r2.y, fmaf(wv.z, r2.z, wv.w * r2.w)));
            a3 += fmaf(wv.x, r3.x, fmaf(wv.y, r3.y, fmaf(wv.z, r3.z, wv.w * r3.w)));
        }
        featS[0 * FEAT_ + o] = (a0 + bias) * scale;
        featS[1 * FEAT_ + o] = (a1 + bias) * scale;
        featS[2 * FEAT_ + o] = (a2 + bias) * scale;
        featS[3 * FEAT_ + o] = (a3 + bias) * scale;
    }
    if (tid < 4) featS[tid * FEAT_ + 320] = d_ot[b0 + tid];
    __syncthreads();

    int w = tid >> 6, lane = tid & 63;
    if (w < 4) {   // wave w handles batch b0+w
        const float* f = featS + w * FEAT_;
        float s = 0.f, s2 = 0.f;
        for (int i = lane; i < FEAT_; i += 64) {
            float v = f[i];
            s += v;
            s2 = fmaf(v, v, s2);
        }
#pragma unroll
        for (int off = 32; off > 0; off >>= 1) {
            s += __shfl_xor(s, off);
            s2 += __shfl_xor(s2, off);
        }
        float mu = s * (1.f / (float)FEAT_);
        float var = fmaxf(s2 * (1.f / (float)FEAT_) - mu * mu, 0.f);
        float rstd = 1.0f / sqrtf(var + LN_EPS_);
        float l0 = 0.f, l1 = 0.f;
        for (int i = lane; i < FEAT_; i += 64) {
            float nv = (f[i] - mu) * rstd * lng[i] + lnb[i];
            l0 = fmaf(nv, Wcls[i], l0);
            l1 = fmaf(nv, Wcls[FEAT_ + i], l1);
        }
#pragma unroll
        for (int off = 32; off > 0; off >>= 1) {
            l0 += __shfl_xor(l0, off);
            l1 += __shfl_xor(l1, off);
        }
        if (lane == 0) {
            out[(size_t)(b0 + w) * 2 + 0] = l0 + bcls[0];
            out[(size_t)(b0 + w) * 2 + 1] = l1 + bcls[1];
        }
    }
}

// ---------------------------------------------------------------------------
// Kernel 5/6: ortho = mean((Wc @ Ws^T)^2), deterministic two-stage reduction
// ---------------------------------------------------------------------------
__global__ __launch_bounds__(256) void k_ortho(const float* __restrict__ Wc,
                                               const float* __restrict__ Ws,
                                               float* __restrict__ part) {
    int i = blockIdx.x;    // Wc row, 0..191
    int tid = threadIdx.x;
    __shared__ float wrow[1536];
    __shared__ float tmp[256];
    for (int k = tid; k < 1536; k += 256) wrow[k] = Wc[(size_t)i * 1536 + k];
    __syncthreads();
    int j = tid & 127, h = tid >> 7;    // split each dot across 2 threads
    const float* wsr = Ws + (size_t)j * 1536 + h * 768;
    const float* wr = wrow + h * 768;
    float s = 0.f;
    for (int k = 0; k < 768; ++k) s = fmaf(wr[k], wsr[k], s);
    tmp[tid] = s;
    __syncthreads();
    if (tid < 128) {
        float d = tmp[tid] + tmp[tid + 128];
        tmp[tid] = d * d;
    }
    __syncthreads();
    for (int off = 64; off > 0; off >>= 1) {
        if (tid < off) tmp[tid] += tmp[tid + off];
        __syncthreads();
    }
    if (tid == 0) part[i] = tmp[0];
}

__global__ __launch_bounds__(256) void k_ortho2(const float* __restrict__ part,
                                                float* __restrict__ out) {
    int tid = threadIdx.x;
    __shared__ float red[256];
    red[tid] = (tid < CD_) ? part[tid] : 0.f;
    __syncthreads();
    for (int off = 128; off > 0; off >>= 1) {
        if (tid < off) red[tid] += red[tid + off];
        __syncthreads();
    }
    if (tid == 0) out[(size_t)B_ * 2] = red[0] / (float)(CD_ * SD_);
}

// ---------------------------------------------------------------------------
extern "C" void kernel_launch(void* const* d_in, const int* in_sizes, int n_in,
                              void* d_out, int out_size, void* d_ws, size_t ws_size,
                              hipStream_t stream) {
    const float* H    = (const float*)d_in[0];
    const int*   tt   = (const int*)d_in[1];
    const int*   attn = (const int*)d_in[2];
    const float* Wc   = (const float*)d_in[3];
    const float* bc   = (const float*)d_in[4];
    const float* Ws   = (const float*)d_in[5];
    const float* bs   = (const float*)d_in[6];
    const float* gate = (const float*)d_in[7];
    const float* lng  = (const float*)d_in[8];
    const float* lnb  = (const float*)d_in[9];
    const float* Wcls = (const float*)d_in[10];
    const float* bcls = (const float*)d_in[11];
    const float* dirs = (const float*)d_in[12];

    float* ws    = (float*)d_ws;
    float* rep   = ws;                                      // [B][1536] fp32
    unsigned short* dn16 = (unsigned short*)(ws + REP_SZ);  // [P][D] bf16
    float* dot   = ws + REP_SZ + DN16_FLT;                  // [B]
    float* part  = dot + B_;                                // [CD]
    float* out   = (float*)d_out;

    k_dirs<<<P_, 256, 0, stream>>>(dirs, dn16);
    k_rep<<<B_, 256, 0, stream>>>(H, tt, attn, rep);
    k_projsort<<<B_, 512, 0, stream>>>(H, tt, attn, dn16, dot);
    k_head<<<B_ / 4, 320, 0, stream>>>(rep, Wc, bc, Ws, bs, gate, lng, lnb, Wcls, bcls, dot, out);
    k_ortho<<<CD_, 256, 0, stream>>>(Wc, Ws, part);
    k_ortho2<<<1, 256, 0, stream>>>(part, out);
}

// Round 5
// 218.737 us; speedup vs baseline: 1.8535x; 1.8535x over previous
//
#include <hip/hip_runtime.h>
#include <hip/hip_bf16.h>

// Problem constants
constexpr int B_ = 512;
constexpr int T_ = 128;
constexpr int D_ = 768;
constexpr int CD_ = 192;
constexpr int SD_ = 128;
constexpr int P_ = 128;
constexpr int FEAT_ = 321;   // CD + SD + 1
constexpr float LN_EPS_ = 1e-5f;

constexpr size_t REP_SZ   = (size_t)B_ * 2 * D_;     // 786432 floats
constexpr size_t DN16_FLT = (size_t)P_ * D_ / 2;     // 98304 u16 = 49152 floats

typedef __attribute__((ext_vector_type(8))) short short8;   // 8 bf16 (4 VGPRs)
typedef __attribute__((ext_vector_type(4))) float f32x4;

// float -> bf16 RNE
__device__ __forceinline__ unsigned short f2bf(float x) {
    unsigned u = __float_as_uint(x);
    return (unsigned short)((u + 0x7FFFu + ((u >> 16) & 1u)) >> 16);
}
__device__ __forceinline__ float bf2f(unsigned short h) {
    return __uint_as_float((unsigned)h << 16);
}

// ---------------------------------------------------------------------------
// Kernel 1: dirs_n = dirs / ||dirs||, emitted as bf16  (one block per dir)
// ---------------------------------------------------------------------------
__global__ __launch_bounds__(256) void k_dirs(const float* __restrict__ dirs,
                                              unsigned short* __restrict__ dn16) {
    int p = blockIdx.x;
    int tid = threadIdx.x;
    float s = 0.f;
    for (int d = tid; d < D_; d += 256) {
        float v = dirs[(size_t)p * D_ + d];
        s = fmaf(v, v, s);
    }
    __shared__ float red[256];
    red[tid] = s;
    __syncthreads();
    for (int off = 128; off > 0; off >>= 1) {
        if (tid < off) red[tid] += red[tid + off];
        __syncthreads();
    }
    float inv = 1.0f / sqrtf(red[0]);
    for (int d = tid; d < D_; d += 256) {
        dn16[(size_t)p * D_ + d] = f2bf(dirs[(size_t)p * D_ + d] * inv);
    }
}

// ---------------------------------------------------------------------------
// Kernel 2: rep = [cls | mmean0 - mmean1]  (one block per batch, streaming)
// ---------------------------------------------------------------------------
__global__ __launch_bounds__(256) void k_rep(const float* __restrict__ H,
                                             const int* __restrict__ tt,
                                             const int* __restrict__ attn,
                                             float* __restrict__ rep) {
    int b = blockIdx.x;
    int tid = threadIdx.x;
    __shared__ float m0s[T_], m1s[T_];
    __shared__ int ncnt[2];
    if (tid < 2) ncnt[tid] = 0;
    __syncthreads();
    if (tid < T_) {
        int t = tt[b * T_ + tid];
        int a = attn[b * T_ + tid];
        float m0 = (t == 0 && a == 1) ? 1.f : 0.f;
        float m1 = (t == 1 && a == 1) ? 1.f : 0.f;
        m0s[tid] = m0;
        m1s[tid] = m1;
        if (m0 > 0.f) atomicAdd(&ncnt[0], 1);
        if (m1 > 0.f) atomicAdd(&ncnt[1], 1);
    }
    __syncthreads();
    float inv0 = 1.f / (float)max(ncnt[0], 1);
    float inv1 = 1.f / (float)max(ncnt[1], 1);
    const float* Hb = H + (size_t)b * T_ * D_;
    float* repb = rep + (size_t)b * 2 * D_;
#pragma unroll
    for (int pass = 0; pass < 3; ++pass) {
        int d = pass * 256 + tid;
        float s0 = 0.f, s1 = 0.f;
#pragma unroll 8
        for (int t = 0; t < T_; ++t) {
            float h = Hb[(size_t)t * D_ + d];
            s0 = fmaf(h, m0s[t], s0);
            s1 = fmaf(h, m1s[t], s1);
        }
        repb[d] = Hb[d];
        repb[D_ + d] = s0 * inv0 - s1 * inv1;
    }
}

// ---------------------------------------------------------------------------
// Kernel 3: MFMA proj GEMM (128x128 tile, bf16, reg-prefetch dbuf LDS,
//           raw barriers, XOR-swizzled stage) + key-rank + paired diff.
// One 512-thread block per batch. proj16 stored group-permuted + sortable-u16.
// ---------------------------------------------------------------------------
constexpr int NIT_ = 24;            // 768 / 32
constexpr int BUF_U16_ = 8192;      // A 4096 + B 4096 u16 per buffer (16 KB)

__global__ __launch_bounds__(512, 2) void k_projsort(const float* __restrict__ H,
                                                     const int* __restrict__ tt,
                                                     const int* __restrict__ attn,
                                                     const unsigned short* __restrict__ dn16,
                                                     float* __restrict__ d_ot) {
    const int b = blockIdx.x;
    const int tid = threadIdx.x;

    __shared__ __align__(16) unsigned short stage[2 * BUF_U16_];  // 32 KB
    __shared__ __align__(16) unsigned short proj16[T_ * 128];     // 32 KB (permuted, sortable-u16)
    __shared__ float m0s[T_], m1s[T_];
    __shared__ unsigned char pos_s[T_];
    __shared__ int ncnt[2];
    __shared__ float dred[512];

    // rank->pos index tables overlay the (dead after GEMM) stage buffer
    unsigned char* xb = (unsigned char*)stage;           // [64][128]
    unsigned char* yb = xb + 64 * 128;                   // [64][128]

    // --- phase 0: masks, counts, row -> group-compacted position map ---
    if (tid < 2) ncnt[tid] = 0;
    __syncthreads();
    if (tid < T_) {
        int t = tt[b * T_ + tid];
        int a = attn[b * T_ + tid];
        float m0 = (t == 0 && a == 1) ? 1.f : 0.f;
        float m1 = (t == 1 && a == 1) ? 1.f : 0.f;
        m0s[tid] = m0;
        m1s[tid] = m1;
        if (m0 > 0.f) atomicAdd(&ncnt[0], 1);
        if (m1 > 0.f) atomicAdd(&ncnt[1], 1);
    }
    __syncthreads();
    const int n0 = ncnt[0], n1 = ncnt[1];
    const int ntot = n0 + n1;
    if (tid < T_) {
        float me0 = m0s[tid], me1 = m1s[tid];
        unsigned char pp = 0xFF;
        if (me0 > 0.f || me1 > 0.f) {
            bool g1 = (me1 > 0.f);
            const float* ms = g1 ? m1s : m0s;
            int pos = g1 ? n0 : 0;
            for (int j = 0; j < tid; ++j) pos += (ms[j] > 0.f) ? 1 : 0;
            pp = (unsigned char)pos;
        }
        pos_s[tid] = pp;
    }
    __syncthreads();

    // --- phase 1: GEMM proj[t][p] = sum_k H[b,t,k] * dn[p,k] via bf16 MFMA ---
    const float* Hb = H + (size_t)b * T_ * D_;
    const int srow = tid >> 2;                 // 0..127
    const int scp  = tid & 3;                  // phys chunk (16 B)
    const int sclog = scp ^ ((srow >> 1) & 3); // logical chunk (swizzle, involution)
    const float* gA = Hb + (size_t)srow * D_ + sclog * 8;
    const unsigned short* gB = dn16 + (size_t)srow * D_ + sclog * 8;
    const int dOff = srow * 32 + scp * 8;      // u16 offset within A region

    // MFMA fragment geometry: 8 waves = 2 (row) x 4 (col)
    const int wv = tid >> 6;
    const int wr = wv >> 2;           // 0..1 : rows 64*wr..
    const int wc = wv & 3;            // 0..3 : cols 32*wc..
    const int lane = tid & 63;
    const int fr = lane & 15;
    const int kg = lane >> 4;
    const int ck = (kg ^ ((fr >> 1) & 3)) * 8;           // swizzled k-chunk
    const int baseA = (64 * wr + fr) * 32 + ck;          // + 512*m
    const int baseB = 4096 + (32 * wc + fr) * 32 + ck;   // + 512*n

    f32x4 acc[4][2];
#pragma unroll
    for (int m = 0; m < 4; ++m)
#pragma unroll
        for (int n = 0; n < 2; ++n) acc[m][n] = (f32x4){0.f, 0.f, 0.f, 0.f};

    // prologue: prefetch k0 = 0
    float4 a0 = *reinterpret_cast<const float4*>(gA);
    float4 a1 = *reinterpret_cast<const float4*>(gA + 4);
    short8 bv = *reinterpret_cast<const short8*>(gB);

    for (int it = 0; it < NIT_; ++it) {
        const int cur = it & 1;
        unsigned short* sb = stage + cur * BUF_U16_;
        // convert + stage current tile
        short8 w;
        w[0] = (short)f2bf(a0.x); w[1] = (short)f2bf(a0.y);
        w[2] = (short)f2bf(a0.z); w[3] = (short)f2bf(a0.w);
        w[4] = (short)f2bf(a1.x); w[5] = (short)f2bf(a1.y);
        w[6] = (short)f2bf(a1.z); w[7] = (short)f2bf(a1.w);
        *reinterpret_cast<short8*>(sb + dOff) = w;
        *reinterpret_cast<short8*>(sb + 4096 + dOff) = bv;
        // prefetch next tile (stays in flight across both barriers + MFMA)
        if (it < NIT_ - 1) {
            int k = (it + 1) * 32;
            a0 = *reinterpret_cast<const float4*>(gA + k);
            a1 = *reinterpret_cast<const float4*>(gA + k + 4);
            bv = *reinterpret_cast<const short8*>(gB + k);
        }
        asm volatile("s_waitcnt lgkmcnt(0)" ::: "memory");
        __builtin_amdgcn_s_barrier();
        asm volatile("" ::: "memory");

        const unsigned short* sr = stage + cur * BUF_U16_;
        short8 af[4], bf_[2];
#pragma unroll
        for (int m = 0; m < 4; ++m)
            af[m] = *reinterpret_cast<const short8*>(sr + baseA + 512 * m);
#pragma unroll
        for (int n = 0; n < 2; ++n)
            bf_[n] = *reinterpret_cast<const short8*>(sr + baseB + 512 * n);
#pragma unroll
        for (int m = 0; m < 4; ++m)
#pragma unroll
            for (int n = 0; n < 2; ++n)
                acc[m][n] = __builtin_amdgcn_mfma_f32_16x16x32_bf16(af[m], bf_[n], acc[m][n], 0, 0, 0);

        asm volatile("" ::: "memory");
        __builtin_amdgcn_s_barrier();
        asm volatile("" ::: "memory");
    }

    // epilogue: write proj16 group-permuted (pos_s) as sortable u16.
    // C/D layout: col=lane&15, row=(lane>>4)*4+reg
#pragma unroll
    for (int m = 0; m < 4; ++m) {
        int row0 = 64 * wr + 16 * m + kg * 4;
#pragma unroll
        for (int r = 0; r < 4; ++r) {
            int pp = pos_s[row0 + r];
            if (pp != 0xFF) {
#pragma unroll
                for (int n = 0; n < 2; ++n) {
                    int col = 32 * wc + 16 * n + fr;
                    unsigned bb = f2bf(acc[m][n][r]);
                    unsigned su = bb ^ ((bb >> 15) ? 0xFFFFu : 0x8000u);
                    proj16[pp * 128 + col] = (unsigned short)su;
                }
            }
        }
    }
    __syncthreads();

    // --- phase 2: ranking via sortable-u32 keys, 2 passes x 16 keys ---
    const int mmv = min(n0, n1);      // <= 64 since n0+n1 <= 128
    const int c = tid & 127;
    const int q = tid >> 7;           // 0..3
#pragma unroll
    for (int pass = 0; pass < 2; ++pass) {
        const int pbase = q * 32 + pass * 16;
        unsigned kv[16];
        int cnt[16];
#pragma unroll
        for (int ii = 0; ii < 16; ++ii) {
            int p = pbase + ii;
            unsigned key = 0xFFFFFFFFu;
            if (p < ntot) {
                unsigned su = proj16[p * 128 + c];
                key = ((unsigned)(p >= n0) << 31) | (su << 8) | (unsigned)p;
            }
            kv[ii] = key;
            cnt[ii] = 0;
        }
        int lo, hi;
        if (pbase + 16 <= n0) { lo = 0;  hi = n0;   }   // pure group-0 chunk
        else if (pbase >= n0) { lo = n0; hi = ntot; }   // pure group-1 chunk
        else                  { lo = 0;  hi = ntot; }   // straddler
        for (int j = lo; j < hi; ++j) {
            unsigned su = proj16[j * 128 + c];
            unsigned kw = ((unsigned)(j >= n0) << 31) | (su << 8) | (unsigned)j;
#pragma unroll
            for (int ii = 0; ii < 16; ++ii) cnt[ii] += (kw < kv[ii]) ? 1 : 0;
        }
#pragma unroll
        for (int ii = 0; ii < 16; ++ii) {
            int p = pbase + ii;
            if (p < ntot) {
                int rank = cnt[ii] - ((p >= n0 && lo == 0) ? n0 : 0);
                if (rank < mmv) {
                    unsigned char* buf = (p >= n0) ? yb : xb;
                    buf[rank * 128 + c] = (unsigned char)p;
                }
            }
        }
    }
    __syncthreads();

    // --- phase 3: paired diff per column, max over columns ---
    float part = 0.f;
    for (int r = q; r < mmv; r += 4) {
        unsigned sx = proj16[(int)xb[r * 128 + c] * 128 + c];
        unsigned sy = proj16[(int)yb[r * 128 + c] * 128 + c];
        unsigned bx = sx ^ ((sx >> 15) ? 0x8000u : 0xFFFFu);
        unsigned by = sy ^ ((sy >> 15) ? 0x8000u : 0xFFFFu);
        part += fabsf(bf2f((unsigned short)bx) - bf2f((unsigned short)by));
    }
    dred[tid] = part;
    __syncthreads();
    if (tid < 128) {
        float invm = 1.f / (float)max(mmv, 1);
        dred[tid] = (dred[tid] + dred[tid + 128] + dred[tid + 256] + dred[tid + 384]) * invm;
    }
    __syncthreads();
    if (tid < 64) {
        float m = fmaxf(dred[tid], dred[tid + 64]);
#pragma unroll
        for (int off = 32; off > 0; off >>= 1) m = fmaxf(m, __shfl_xor(m, off));
        if (tid == 0) d_ot[b] = m;    // one block per batch: direct store
    }
}

// ---------------------------------------------------------------------------
// Kernel 4: head — C/S GEMV + gate + LayerNorm + logits.
// 320 threads (1 output each), 4 batches per block, wave-parallel LN.
// ---------------------------------------------------------------------------
__global__ __launch_bounds__(320) void k_head(const float* __restrict__ rep,
                                              const float* __restrict__ Wc,
                                              const float* __restrict__ bc,
                                              const float* __restrict__ Ws,
                                              const float* __restrict__ bs,
                                              const float* __restrict__ gate,
                                              const float* __restrict__ lng,
                                              const float* __restrict__ lnb,
                                              const float* __restrict__ Wcls,
                                              const float* __restrict__ bcls,
                                              const float* __restrict__ d_ot,
                                              float* __restrict__ out) {
    int b0 = blockIdx.x * 4;
    int tid = threadIdx.x;
    __shared__ __align__(16) float repS[4 * 1536];   // 24 KB
    __shared__ float featS[4 * FEAT_];

    const float4* repg = reinterpret_cast<const float4*>(rep + (size_t)b0 * 1536);
    float4* repl = reinterpret_cast<float4*>(repS);
    for (int i = tid; i < 1536; i += 320) repl[i] = repg[i];
    __syncthreads();

    float g = 1.f / (1.f + expf(-gate[0]));

    {   // each thread: one output o over 4 batches
        int o = tid;  // 0..319
        bool isC = o < CD_;
        const float* w = isC ? (Wc + (size_t)o * 1536) : (Ws + (size_t)(o - CD_) * 1536);
        float bias = isC ? bc[o] : bs[o - CD_];
        float scale = isC ? (1.f - g) : g;
        const float4* w4 = reinterpret_cast<const float4*>(w);
        float a0 = 0.f, a1 = 0.f, a2 = 0.f, a3 = 0.f;
        for (int k4 = 0; k4 < 384; ++k4) {
            float4 wv = w4[k4];
            float4 r0 = repl[k4];
            float4 r1 = repl[384 + k4];
            float4 r2 = repl[768 + k4];
            float4 r3 = repl[1152 + k4];
            a0 += fmaf(wv.x, r0.x, fmaf(wv.y, r0.y, fmaf(wv.z, r0.z, wv.w * r0.w)));
            a1 += fmaf(wv.x, r1.x, fmaf(wv.y, r1.y, fmaf(wv.z, r1.z, wv.w * r1.w)));
            a2 += fmaf(wv.x, r2.x, fmaf(wv.y, r2.y, fmaf(wv.z, r2.z, wv.w * r2.w)));
            a3 += fmaf(wv.x, r3.x, fmaf(wv.y, r3.y, fmaf(wv.z, r3.z, wv.w * r3.w)));
        }
        featS[0 * FEAT_ + o] = (a0 + bias) * scale;
        featS[1 * FEAT_ + o] = (a1 + bias) * scale;
        featS[2 * FEAT_ + o] = (a2 + bias) * scale;
        featS[3 * FEAT_ + o] = (a3 + bias) * scale;
    }
    if (tid < 4) featS[tid * FEAT_ + 320] = d_ot[b0 + tid];
    __syncthreads();

    int w = tid >> 6, lane = tid & 63;
    if (w < 4) {   // wave w handles batch b0+w
        const float* f = featS + w * FEAT_;
        float s = 0.f, s2 = 0.f;
        for (int i = lane; i < FEAT_; i += 64) {
            float v = f[i];
            s += v;
            s2 = fmaf(v, v, s2);
        }
#pragma unroll
        for (int off = 32; off > 0; off >>= 1) {
            s += __shfl_xor(s, off);
            s2 += __shfl_xor(s2, off);
        }
        float mu = s * (1.f / (float)FEAT_);
        float var = fmaxf(s2 * (1.f / (float)FEAT_) - mu * mu, 0.f);
        float rstd = 1.0f / sqrtf(var + LN_EPS_);
        float l0 = 0.f, l1 = 0.f;
        for (int i = lane; i < FEAT_; i += 64) {
            float nv = (f[i] - mu) * rstd * lng[i] + lnb[i];
            l0 = fmaf(nv, Wcls[i], l0);
            l1 = fmaf(nv, Wcls[FEAT_ + i], l1);
        }
#pragma unroll
        for (int off = 32; off > 0; off >>= 1) {
            l0 += __shfl_xor(l0, off);
            l1 += __shfl_xor(l1, off);
        }
        if (lane == 0) {
            out[(size_t)(b0 + w) * 2 + 0] = l0 + bcls[0];
            out[(size_t)(b0 + w) * 2 + 1] = l1 + bcls[1];
        }
    }
}

// ---------------------------------------------------------------------------
// Kernel 5/6: ortho = mean((Wc @ Ws^T)^2), deterministic two-stage reduction
// ---------------------------------------------------------------------------
__global__ __launch_bounds__(256) void k_ortho(const float* __restrict__ Wc,
                                               const float* __restrict__ Ws,
                                               float* __restrict__ part) {
    int i = blockIdx.x;    // Wc row, 0..191
    int tid = threadIdx.x;
    __shared__ float wrow[1536];
    __shared__ float tmp[256];
    for (int k = tid; k < 1536; k += 256) wrow[k] = Wc[(size_t)i * 1536 + k];
    __syncthreads();
    int j = tid & 127, h = tid >> 7;    // split each dot across 2 threads
    const float* wsr = Ws + (size_t)j * 1536 + h * 768;
    const float* wr = wrow + h * 768;
    float s = 0.f;
    for (int k = 0; k < 768; ++k) s = fmaf(wr[k], wsr[k], s);
    tmp[tid] = s;
    __syncthreads();
    if (tid < 128) {
        float d = tmp[tid] + tmp[tid + 128];
        tmp[tid] = d * d;
    }
    __syncthreads();
    for (int off = 64; off > 0; off >>= 1) {
        if (tid < off) tmp[tid] += tmp[tid + off];
        __syncthreads();
    }
    if (tid == 0) part[i] = tmp[0];
}

__global__ __launch_bounds__(256) void k_ortho2(const float* __restrict__ part,
                                                float* __restrict__ out) {
    int tid = threadIdx.x;
    __shared__ float red[256];
    red[tid] = (tid < CD_) ? part[tid] : 0.f;
    __syncthreads();
    for (int off = 128; off > 0; off >>= 1) {
        if (tid < off) red[tid] += red[tid + off];
        __syncthreads();
    }
    if (tid == 0) out[(size_t)B_ * 2] = red[0] / (float)(CD_ * SD_);
}

// ---------------------------------------------------------------------------
extern "C" void kernel_launch(void* const* d_in, const int* in_sizes, int n_in,
                              void* d_out, int out_size, void* d_ws, size_t ws_size,
                              hipStream_t stream) {
    const float* H    = (const float*)d_in[0];
    const int*   tt   = (const int*)d_in[1];
    const int*   attn = (const int*)d_in[2];
    const float* Wc   = (const float*)d_in[3];
    const float* bc   = (const float*)d_in[4];
    const float* Ws   = (const float*)d_in[5];
    const float* bs   = (const float*)d_in[6];
    const float* gate = (const float*)d_in[7];
    const float* lng  = (const float*)d_in[8];
    const float* lnb  = (const float*)d_in[9];
    const float* Wcls = (const float*)d_in[10];
    const float* bcls = (const float*)d_in[11];
    const float* dirs = (const float*)d_in[12];

    float* ws    = (float*)d_ws;
    float* rep   = ws;                                      // [B][1536] fp32
    unsigned short* dn16 = (unsigned short*)(ws + REP_SZ);  // [P][D] bf16
    float* dot   = ws + REP_SZ + DN16_FLT;                  // [B]
    float* part  = dot + B_;                                // [CD]
    float* out   = (float*)d_out;

    k_dirs<<<P_, 256, 0, stream>>>(dirs, dn16);
    k_rep<<<B_, 256, 0, stream>>>(H, tt, attn, rep);
    k_projsort<<<B_, 512, 0, stream>>>(H, tt, attn, dn16, dot);
    k_head<<<B_ / 4, 320, 0, stream>>>(rep, Wc, bc, Ws, bs, gate, lng, lnb, Wcls, bcls, dot, out);
    k_ortho<<<CD_, 256, 0, stream>>>(Wc, Ws, part);
    k_ortho2<<<1, 256, 0, stream>>>(part, out);
}

// Round 6
// 191.337 us; speedup vs baseline: 2.1189x; 1.1432x over previous
//
#include <hip/hip_runtime.h>
#include <hip/hip_bf16.h>

// Problem constants
constexpr int B_ = 512;
constexpr int T_ = 128;
constexpr int D_ = 768;
constexpr int CD_ = 192;
constexpr int SD_ = 128;
constexpr int P_ = 128;
constexpr int FEAT_ = 321;   // CD + SD + 1
constexpr float LN_EPS_ = 1e-5f;

constexpr size_t REP_SZ   = (size_t)B_ * 2 * D_;     // 786432 floats
constexpr size_t DN16_FLT = (size_t)P_ * D_ / 2;     // 98304 u16 = 49152 floats

typedef __attribute__((ext_vector_type(8))) short short8;   // 8 bf16 (4 VGPRs)
typedef __attribute__((ext_vector_type(4))) float f32x4;

// float -> bf16 RNE
__device__ __forceinline__ unsigned short f2bf(float x) {
    unsigned u = __float_as_uint(x);
    return (unsigned short)((u + 0x7FFFu + ((u >> 16) & 1u)) >> 16);
}
__device__ __forceinline__ float bf2f(unsigned short h) {
    return __uint_as_float((unsigned)h << 16);
}

// ---------------------------------------------------------------------------
// Kernel 1: dirs_n = dirs / ||dirs||, emitted as bf16  (one block per dir)
// ---------------------------------------------------------------------------
__global__ __launch_bounds__(256) void k_dirs(const float* __restrict__ dirs,
                                              unsigned short* __restrict__ dn16) {
    int p = blockIdx.x;
    int tid = threadIdx.x;
    float s = 0.f;
    for (int d = tid; d < D_; d += 256) {
        float v = dirs[(size_t)p * D_ + d];
        s = fmaf(v, v, s);
    }
    __shared__ float red[256];
    red[tid] = s;
    __syncthreads();
    for (int off = 128; off > 0; off >>= 1) {
        if (tid < off) red[tid] += red[tid + off];
        __syncthreads();
    }
    float inv = 1.0f / sqrtf(red[0]);
    for (int d = tid; d < D_; d += 256) {
        dn16[(size_t)p * D_ + d] = f2bf(dirs[(size_t)p * D_ + d] * inv);
    }
}

// ---------------------------------------------------------------------------
// Kernel 2: MFMA proj GEMM (128x128 tile, bf16, depth-2 reg prefetch, dbuf LDS,
//           raw barriers, XOR-swizzled stage) + FUSED rep (mask-MFMA on a
//           transposed Ht tile) + key-rank + paired diff.
// One 512-thread block per batch. proj16 stored group-permuted + sortable-u16.
// ---------------------------------------------------------------------------
constexpr int NIT_ = 24;            // 768 / 32
constexpr int BUF_U16_ = 8192;      // A 4096 + B 4096 u16 per buffer (16 KB)
constexpr int HT_STR_ = 136;        // Ht row stride in u16 (272 B, 16B-aligned)

__global__ __launch_bounds__(512, 2) void k_projsort(const float* __restrict__ H,
                                                     const int* __restrict__ tt,
                                                     const int* __restrict__ attn,
                                                     const unsigned short* __restrict__ dn16,
                                                     float* __restrict__ rep,
                                                     float* __restrict__ d_ot) {
    const int b = blockIdx.x;
    const int tid = threadIdx.x;

    __shared__ __align__(16) unsigned short stage[2 * BUF_U16_];   // 32 KB
    __shared__ __align__(16) unsigned short Ht[32 * HT_STR_];      // 8.5 KB transposed A-slice
    __shared__ __align__(16) unsigned short proj16[T_ * 128];      // 32 KB (permuted, sortable-u16)
    __shared__ __align__(16) unsigned short mask16[2 * T_];        // bf16 masks (exact 0/1)
    __shared__ float m0s[T_], m1s[T_];
    __shared__ unsigned char pos_s[T_];
    __shared__ int ncnt[2];
    __shared__ float dred[512];

    // rank->pos index tables overlay the (dead after GEMM) stage buffer
    unsigned char* xb = (unsigned char*)stage;           // [64][128]
    unsigned char* yb = xb + 64 * 128;                   // [64][128]

    // --- staging geometry; issue the first two tiles' loads ASAP ---
    const float* Hb = H + (size_t)b * T_ * D_;
    const int srow = tid >> 2;                 // 0..127
    const int scp  = tid & 3;                  // phys 16B chunk
    const int sclog = scp ^ ((srow >> 1) & 3); // logical chunk (swizzle, involution)
    const float* gA = Hb + (size_t)srow * D_ + sclog * 8;
    const unsigned short* gB = dn16 + (size_t)srow * D_ + sclog * 8;
    const int dOff = srow * 32 + scp * 8;      // u16 offset within A region

    float4 a0A = *reinterpret_cast<const float4*>(gA);
    float4 a1A = *reinterpret_cast<const float4*>(gA + 4);
    short8 bvA = *reinterpret_cast<const short8*>(gB);
    float4 a0B = *reinterpret_cast<const float4*>(gA + 32);
    float4 a1B = *reinterpret_cast<const float4*>(gA + 36);
    short8 bvB = *reinterpret_cast<const short8*>(gB + 32);

    // --- phase 0: masks, counts, pos map, bf16 mask rows ---
    if (tid < 2) ncnt[tid] = 0;
    __syncthreads();
    if (tid < T_) {
        int t = tt[b * T_ + tid];
        int a = attn[b * T_ + tid];
        float m0 = (t == 0 && a == 1) ? 1.f : 0.f;
        float m1 = (t == 1 && a == 1) ? 1.f : 0.f;
        m0s[tid] = m0;
        m1s[tid] = m1;
        mask16[tid] = (m0 > 0.f) ? 0x3F80u : 0u;        // bf16 1.0 / 0.0
        mask16[T_ + tid] = (m1 > 0.f) ? 0x3F80u : 0u;
        if (m0 > 0.f) atomicAdd(&ncnt[0], 1);
        if (m1 > 0.f) atomicAdd(&ncnt[1], 1);
    }
    __syncthreads();
    const int n0 = ncnt[0], n1 = ncnt[1];
    const int ntot = n0 + n1;
    const float inv0 = 1.f / (float)max(n0, 1);
    const float inv1 = 1.f / (float)max(n1, 1);
    if (tid < T_) {
        float me0 = m0s[tid], me1 = m1s[tid];
        unsigned char pp = 0xFF;
        if (me0 > 0.f || me1 > 0.f) {
            bool g1 = (me1 > 0.f);
            const float* ms = g1 ? m1s : m0s;
            int pos = g1 ? n0 : 0;
            for (int j = 0; j < tid; ++j) pos += (ms[j] > 0.f) ? 1 : 0;
            pp = (unsigned char)pos;
        }
        pos_s[tid] = pp;
    }
    __syncthreads();

    // --- phase 1: proj GEMM + fused rep ---
    const int wv = tid >> 6;          // wave 0..7
    const int wr = wv >> 2;           // 0..1 : row half
    const int wc = wv & 3;            // 0..3 : col quarter
    const int lane = tid & 63;
    const int fr = lane & 15;
    const int kg = lane >> 4;
    const int fk = kg * 8;
    const int ck = (kg ^ ((fr >> 1) & 3)) * 8;           // swizzled k-chunk
    const int baseA = (64 * wr + fr) * 32 + ck;          // + 512*m
    const int baseB = 4096 + (32 * wc + 16 * 0 + fr) * 32 + ck;  // + 512*n
    const bool repw = (wv >= 6);      // waves 6,7 also compute rep
    const int jf = wv & 1;            // rep d-halve per rep-wave
    float* repb = rep + (size_t)b * 2 * D_;

    f32x4 acc[4][2];
#pragma unroll
    for (int m = 0; m < 4; ++m)
#pragma unroll
        for (int n = 0; n < 2; ++n) acc[m][n] = (f32x4){0.f, 0.f, 0.f, 0.f};

    auto body = [&](int it, unsigned short* sb, float4& pa0, float4& pa1, short8& pbv) {
        // stage current tile (convert + A row-major + Ht transposed + B)
        short8 w;
        w[0] = (short)f2bf(pa0.x); w[1] = (short)f2bf(pa0.y);
        w[2] = (short)f2bf(pa0.z); w[3] = (short)f2bf(pa0.w);
        w[4] = (short)f2bf(pa1.x); w[5] = (short)f2bf(pa1.y);
        w[6] = (short)f2bf(pa1.z); w[7] = (short)f2bf(pa1.w);
        *reinterpret_cast<short8*>(sb + dOff) = w;
        *reinterpret_cast<short8*>(sb + 4096 + dOff) = pbv;
#pragma unroll
        for (int j = 0; j < 8; ++j)
            Ht[(sclog * 8 + j) * HT_STR_ + srow] = (unsigned short)w[j];
        if (srow == 0) {   // cls = H[b,0,:] exact fp32
            *reinterpret_cast<float4*>(repb + it * 32 + sclog * 8) = pa0;
            *reinterpret_cast<float4*>(repb + it * 32 + sclog * 8 + 4) = pa1;
        }
        // prefetch tile it+2 (stays in flight across 2 full iterations)
        if (it + 2 < NIT_) {
            pa0 = *reinterpret_cast<const float4*>(gA + (it + 2) * 32);
            pa1 = *reinterpret_cast<const float4*>(gA + (it + 2) * 32 + 4);
            pbv = *reinterpret_cast<const short8*>(gB + (it + 2) * 32);
        }
        asm volatile("s_waitcnt lgkmcnt(0)" ::: "memory");
        __builtin_amdgcn_s_barrier();
        asm volatile("" ::: "memory");

        short8 af[4], bf_[2];
#pragma unroll
        for (int m = 0; m < 4; ++m)
            af[m] = *reinterpret_cast<const short8*>(sb + baseA + 512 * m);
#pragma unroll
        for (int n = 0; n < 2; ++n)
            bf_[n] = *reinterpret_cast<const short8*>(sb + baseB + 512 * n);
#pragma unroll
        for (int m = 0; m < 4; ++m)
#pragma unroll
            for (int n = 0; n < 2; ++n)
                acc[m][n] = __builtin_amdgcn_mfma_f32_16x16x32_bf16(af[m], bf_[n], acc[m][n], 0, 0, 0);

        if (repw) {   // rep partial: S(2 x 32d) = M(2 x 128t) . Ht(32d x 128t)^T
            f32x4 ar = (f32x4){0.f, 0.f, 0.f, 0.f};
#pragma unroll
            for (int tc = 0; tc < 4; ++tc) {
                short8 am = {0, 0, 0, 0, 0, 0, 0, 0};
                if (fr < 2) am = *reinterpret_cast<const short8*>(&mask16[fr * T_ + tc * 32 + fk]);
                short8 bm = *reinterpret_cast<const short8*>(&Ht[(16 * jf + fr) * HT_STR_ + tc * 32 + fk]);
                ar = __builtin_amdgcn_mfma_f32_16x16x32_bf16(am, bm, ar, 0, 0, 0);
            }
            // C/D layout: col=lane&15, row=reg (lanes 0..15). row0=s0, row1=s1.
            if (lane < 16) repb[D_ + it * 32 + jf * 16 + lane] = ar[0] * inv0 - ar[1] * inv1;
        }
        asm volatile("" ::: "memory");
        __builtin_amdgcn_s_barrier();
        asm volatile("" ::: "memory");
    };

    for (int i2 = 0; i2 < NIT_ / 2; ++i2) {
        body(2 * i2,     stage,            a0A, a1A, bvA);
        body(2 * i2 + 1, stage + BUF_U16_, a0B, a1B, bvB);
    }

    // epilogue: write proj16 group-permuted (pos_s) as sortable u16.
#pragma unroll
    for (int m = 0; m < 4; ++m) {
        int row0 = 64 * wr + 16 * m + kg * 4;
#pragma unroll
        for (int r = 0; r < 4; ++r) {
            int pp = pos_s[row0 + r];
            if (pp != 0xFF) {
#pragma unroll
                for (int n = 0; n < 2; ++n) {
                    int col = 32 * wc + 16 * n + fr;
                    unsigned bb = f2bf(acc[m][n][r]);
                    unsigned su = bb ^ ((bb >> 15) ? 0xFFFFu : 0x8000u);
                    proj16[pp * 128 + col] = (unsigned short)su;
                }
            }
        }
    }
    __syncthreads();

    // --- phase 2: ranking via sortable-u32 keys, 2 passes x 16 keys ---
    const int mmv = min(n0, n1);      // <= 64 since n0+n1 <= 128
    const int c = tid & 127;
    const int q = tid >> 7;           // 0..3
#pragma unroll
    for (int pass = 0; pass < 2; ++pass) {
        const int pbase = q * 32 + pass * 16;
        unsigned kv[16];
        int cnt[16];
#pragma unroll
        for (int ii = 0; ii < 16; ++ii) {
            int p = pbase + ii;
            unsigned key = 0xFFFFFFFFu;
            if (p < ntot) {
                unsigned su = proj16[p * 128 + c];
                key = ((unsigned)(p >= n0) << 31) | (su << 8) | (unsigned)p;
            }
            kv[ii] = key;
            cnt[ii] = 0;
        }
        int lo, hi;
        if (pbase + 16 <= n0) { lo = 0;  hi = n0;   }   // pure group-0 chunk
        else if (pbase >= n0) { lo = n0; hi = ntot; }   // pure group-1 chunk
        else                  { lo = 0;  hi = ntot; }   // straddler
        for (int j = lo; j < hi; ++j) {
            unsigned su = proj16[j * 128 + c];
            unsigned kw = ((unsigned)(j >= n0) << 31) | (su << 8) | (unsigned)j;
#pragma unroll
            for (int ii = 0; ii < 16; ++ii) cnt[ii] += (kw < kv[ii]) ? 1 : 0;
        }
#pragma unroll
        for (int ii = 0; ii < 16; ++ii) {
            int p = pbase + ii;
            if (p < ntot) {
                int rank = cnt[ii] - ((p >= n0 && lo == 0) ? n0 : 0);
                if (rank < mmv) {
                    unsigned char* buf = (p >= n0) ? yb : xb;
                    buf[rank * 128 + c] = (unsigned char)p;
                }
            }
        }
    }
    __syncthreads();

    // --- phase 3: paired diff per column, max over columns ---
    float part = 0.f;
    for (int r = q; r < mmv; r += 4) {
        unsigned sx = proj16[(int)xb[r * 128 + c] * 128 + c];
        unsigned sy = proj16[(int)yb[r * 128 + c] * 128 + c];
        unsigned bx = sx ^ ((sx >> 15) ? 0x8000u : 0xFFFFu);
        unsigned by = sy ^ ((sy >> 15) ? 0x8000u : 0xFFFFu);
        part += fabsf(bf2f((unsigned short)bx) - bf2f((unsigned short)by));
    }
    dred[tid] = part;
    __syncthreads();
    if (tid < 128) {
        float invm = 1.f / (float)max(mmv, 1);
        dred[tid] = (dred[tid] + dred[tid + 128] + dred[tid + 256] + dred[tid + 384]) * invm;
    }
    __syncthreads();
    if (tid < 64) {
        float m = fmaxf(dred[tid], dred[tid + 64]);
#pragma unroll
        for (int off = 32; off > 0; off >>= 1) m = fmaxf(m, __shfl_xor(m, off));
        if (tid == 0) d_ot[b] = m;    // one block per batch: direct store
    }
}

// ---------------------------------------------------------------------------
// Kernel 3: head — C/S GEMV + gate + LayerNorm + logits.
// 320 threads (1 output each), 4 batches per block, wave-parallel LN.
// ---------------------------------------------------------------------------
__global__ __launch_bounds__(320) void k_head(const float* __restrict__ rep,
                                              const float* __restrict__ Wc,
                                              const float* __restrict__ bc,
                                              const float* __restrict__ Ws,
                                              const float* __restrict__ bs,
                                              const float* __restrict__ gate,
                                              const float* __restrict__ lng,
                                              const float* __restrict__ lnb,
                                              const float* __restrict__ Wcls,
                                              const float* __restrict__ bcls,
                                              const float* __restrict__ d_ot,
                                              float* __restrict__ out) {
    int b0 = blockIdx.x * 4;
    int tid = threadIdx.x;
    __shared__ __align__(16) float repS[4 * 1536];   // 24 KB
    __shared__ float featS[4 * FEAT_];

    const float4* repg = reinterpret_cast<const float4*>(rep + (size_t)b0 * 1536);
    float4* repl = reinterpret_cast<float4*>(repS);
    for (int i = tid; i < 1536; i += 320) repl[i] = repg[i];
    __syncthreads();

    float g = 1.f / (1.f + expf(-gate[0]));

    {   // each thread: one output o over 4 batches
        int o = tid;  // 0..319
        bool isC = o < CD_;
        const float* w = isC ? (Wc + (size_t)o * 1536) : (Ws + (size_t)(o - CD_) * 1536);
        float bias = isC ? bc[o] : bs[o - CD_];
        float scale = isC ? (1.f - g) : g;
        const float4* w4 = reinterpret_cast<const float4*>(w);
        float a0 = 0.f, a1 = 0.f, a2 = 0.f, a3 = 0.f;
        for (int k4 = 0; k4 < 384; ++k4) {
            float4 wv = w4[k4];
            float4 r0 = repl[k4];
            float4 r1 = repl[384 + k4];
            float4 r2 = repl[768 + k4];
            float4 r3 = repl[1152 + k4];
            a0 += fmaf(wv.x, r0.x, fmaf(wv.y, r0.y, fmaf(wv.z, r0.z, wv.w * r0.w)));
            a1 += fmaf(wv.x, r1.x, fmaf(wv.y, r1.y, fmaf(wv.z, r1.z, wv.w * r1.w)));
            a2 += fmaf(wv.x, r2.x, fmaf(wv.y, r2.y, fmaf(wv.z, r2.z, wv.w * r2.w)));
            a3 += fmaf(wv.x, r3.x, fmaf(wv.y, r3.y, fmaf(wv.z, r3.z, wv.w * r3.w)));
        }
        featS[0 * FEAT_ + o] = (a0 + bias) * scale;
        featS[1 * FEAT_ + o] = (a1 + bias) * scale;
        featS[2 * FEAT_ + o] = (a2 + bias) * scale;
        featS[3 * FEAT_ + o] = (a3 + bias) * scale;
    }
    if (tid < 4) featS[tid * FEAT_ + 320] = d_ot[b0 + tid];
    __syncthreads();

    int w = tid >> 6, lane = tid & 63;
    if (w < 4) {   // wave w handles batch b0+w
        const float* f = featS + w * FEAT_;
        float s = 0.f, s2 = 0.f;
        for (int i = lane; i < FEAT_; i += 64) {
            float v = f[i];
            s += v;
            s2 = fmaf(v, v, s2);
        }
#pragma unroll
        for (int off = 32; off > 0; off >>= 1) {
            s += __shfl_xor(s, off);
            s2 += __shfl_xor(s2, off);
        }
        float mu = s * (1.f / (float)FEAT_);
        float var = fmaxf(s2 * (1.f / (float)FEAT_) - mu * mu, 0.f);
        float rstd = 1.0f / sqrtf(var + LN_EPS_);
        float l0 = 0.f, l1 = 0.f;
        for (int i = lane; i < FEAT_; i += 64) {
            float nv = (f[i] - mu) * rstd * lng[i] + lnb[i];
            l0 = fmaf(nv, Wcls[i], l0);
            l1 = fmaf(nv, Wcls[FEAT_ + i], l1);
        }
#pragma unroll
        for (int off = 32; off > 0; off >>= 1) {
            l0 += __shfl_xor(l0, off);
            l1 += __shfl_xor(l1, off);
        }
        if (lane == 0) {
            out[(size_t)(b0 + w) * 2 + 0] = l0 + bcls[0];
            out[(size_t)(b0 + w) * 2 + 1] = l1 + bcls[1];
        }
    }
}

// ---------------------------------------------------------------------------
// Kernel 4/5: ortho = mean((Wc @ Ws^T)^2), deterministic two-stage reduction
// ---------------------------------------------------------------------------
__global__ __launch_bounds__(256) void k_ortho(const float* __restrict__ Wc,
                                               const float* __restrict__ Ws,
                                               float* __restrict__ part) {
    int i = blockIdx.x;    // Wc row, 0..191
    int tid = threadIdx.x;
    __shared__ float wrow[1536];
    __shared__ float tmp[256];
    for (int k = tid; k < 1536; k += 256) wrow[k] = Wc[(size_t)i * 1536 + k];
    __syncthreads();
    int j = tid & 127, h = tid >> 7;    // split each dot across 2 threads
    const float* wsr = Ws + (size_t)j * 1536 + h * 768;
    const float* wr = wrow + h * 768;
    float s = 0.f;
    for (int k = 0; k < 768; ++k) s = fmaf(wr[k], wsr[k], s);
    tmp[tid] = s;
    __syncthreads();
    if (tid < 128) {
        float d = tmp[tid] + tmp[tid + 128];
        tmp[tid] = d * d;
    }
    __syncthreads();
    for (int off = 64; off > 0; off >>= 1) {
        if (tid < off) tmp[tid] += tmp[tid + off];
        __syncthreads();
    }
    if (tid == 0) part[i] = tmp[0];
}

__global__ __launch_bounds__(256) void k_ortho2(const float* __restrict__ part,
                                                float* __restrict__ out) {
    int tid = threadIdx.x;
    __shared__ float red[256];
    red[tid] = (tid < CD_) ? part[tid] : 0.f;
    __syncthreads();
    for (int off = 128; off > 0; off >>= 1) {
        if (tid < off) red[tid] += red[tid + off];
        __syncthreads();
    }
    if (tid == 0) out[(size_t)B_ * 2] = red[0] / (float)(CD_ * SD_);
}

// ---------------------------------------------------------------------------
extern "C" void kernel_launch(void* const* d_in, const int* in_sizes, int n_in,
                              void* d_out, int out_size, void* d_ws, size_t ws_size,
                              hipStream_t stream) {
    const float* H    = (const float*)d_in[0];
    const int*   tt   = (const int*)d_in[1];
    const int*   attn = (const int*)d_in[2];
    const float* Wc   = (const float*)d_in[3];
    const float* bc   = (const float*)d_in[4];
    const float* Ws   = (const float*)d_in[5];
    const float* bs   = (const float*)d_in[6];
    const float* gate = (const float*)d_in[7];
    const float* lng  = (const float*)d_in[8];
    const float* lnb  = (const float*)d_in[9];
    const float* Wcls = (const float*)d_in[10];
    const float* bcls = (const float*)d_in[11];
    const float* dirs = (const float*)d_in[12];

    float* ws    = (float*)d_ws;
    float* rep   = ws;                                      // [B][1536] fp32
    unsigned short* dn16 = (unsigned short*)(ws + REP_SZ);  // [P][D] bf16
    float* dot   = ws + REP_SZ + DN16_FLT;                  // [B]
    float* part  = dot + B_;                                // [CD]
    float* out   = (float*)d_out;

    k_dirs<<<P_, 256, 0, stream>>>(dirs, dn16);
    k_projsort<<<B_, 512, 0, stream>>>(H, tt, attn, dn16, rep, dot);
    k_head<<<B_ / 4, 320, 0, stream>>>(rep, Wc, bc, Ws, bs, gate, lng, lnb, Wcls, bcls, dot, out);
    k_ortho<<<CD_, 256, 0, stream>>>(Wc, Ws, part);
    k_ortho2<<<1, 256, 0, stream>>>(part, out);
}